// Round 4
// baseline (4105.069 us; speedup 1.0000x reference)
//
#include <hip/hip_runtime.h>
#include <hip/hip_bf16.h>
#include <math.h>

// Problem constants
#define BB_ 16          // images
#define PP_ 1000        // proposals per image
#define CC_ 91          // classes incl background
#define FF_ 1024        // feature dim
#define DETS_ 100
#define CAP_ 2048       // candidate capacity per image (expected ~320)
#define CAND_MAX (BB_ * CAP_)
#define IMG_W 800.0f
#define IMG_H 800.0f
#define OFF_ 802.0f     // max(H,W)+2
#define SCORE_TH 0.05f
#define NMS_TH 0.5f
#define MIN_SZ 0.01f
#define BBOX_CLIP_D 4.135166556742356   // log(1000/16), rounded to fp32 at use

// ---------------------------------------------------------------------------
// Kernel 1: logits GEMM in FP64 accumulation (64 rows x 91 cols per block),
// FP64 softmax, candidate selection. Score bits land within the references'
// mutual fp32-error band on every borderline comparison.
// ---------------------------------------------------------------------------
__global__ __launch_bounds__(256) void logits_cand(
    const float* __restrict__ A, const float* __restrict__ Wc,
    const float* __restrict__ bc,
    float* __restrict__ cs, int* __restrict__ clab,
    int* __restrict__ corig, int* __restrict__ cpidx,
    int* __restrict__ cnt)
{
    __shared__ float As[16][65];   // [k][m]
    __shared__ float Bs[16][97];   // [k][n]
    __shared__ float Ssc[64][97];  // fp32 logits tile

    const int tid = threadIdx.x;
    const int row0 = blockIdx.x * 64;
    const int tx = tid & 15, ty = tid >> 4;
    const int ty4 = ty * 4, tx6 = tx * 6;

    const int am = tid >> 2;
    const int ak = (tid & 3) * 4;
    const int bk = tid >> 4;
    const int bn = (tid & 15) * 6;

    double acc[4][6];
#pragma unroll
    for (int i = 0; i < 4; ++i)
#pragma unroll
        for (int j = 0; j < 6; ++j) acc[i][j] = 0.0;

    for (int k0 = 0; k0 < FF_; k0 += 16) {
        const float4 av = *reinterpret_cast<const float4*>(
            A + (size_t)(row0 + am) * FF_ + k0 + ak);
        As[ak + 0][am] = av.x;
        As[ak + 1][am] = av.y;
        As[ak + 2][am] = av.z;
        As[ak + 3][am] = av.w;

        const int krow = k0 + bk;
#pragma unroll
        for (int jj = 0; jj < 6; ++jj) {
            const int c = bn + jj;
            Bs[bk][bn + jj] = (c < CC_) ? Wc[(size_t)krow * CC_ + c] : 0.f;
        }
        __syncthreads();

#pragma unroll
        for (int k = 0; k < 16; ++k) {
            float a[4], b[6];
#pragma unroll
            for (int i = 0; i < 4; ++i) a[i] = As[k][ty4 + i];
#pragma unroll
            for (int j = 0; j < 6; ++j) b[j] = Bs[k][tx6 + j];
#pragma unroll
            for (int i = 0; i < 4; ++i)
#pragma unroll
                for (int j = 0; j < 6; ++j)
                    acc[i][j] += (double)a[i] * (double)b[j];
        }
        __syncthreads();
    }

    // fp32 logits (+bias, bias is zeros but replicate ref op order)
#pragma unroll
    for (int i = 0; i < 4; ++i)
#pragma unroll
        for (int j = 0; j < 6; ++j) {
            const int c = tx6 + j;
            if (c < CC_) {
                const float lf = (float)acc[i][j];
                Ssc[ty4 + i][c] = __fadd_rn(lf, bc[c]);
            }
        }
    __syncthreads();

    // per-row fp64 softmax + threshold; threads 0..63 (one row each)
    if (tid < 64) {
        const int p = row0 + tid;
        const int b = p / PP_;
        const int pi = p - b * PP_;

        float m = Ssc[tid][0];
        for (int c = 1; c < CC_; ++c) m = fmaxf(m, Ssc[tid][c]);
        double denom = 0.0;
        for (int c = 0; c < CC_; ++c)
            denom += exp((double)Ssc[tid][c] - (double)m);

        for (int c = 1; c < CC_; ++c) {
            const double sd = exp((double)Ssc[tid][c] - (double)m) / denom;
            const float score = (float)sd;
            if (score > SCORE_TH) {
                const int pos = atomicAdd(&cnt[b], 1);
                if (pos < CAP_) {
                    const int g = b * CAP_ + pos;
                    cs[g] = score;
                    clab[g] = c;
                    corig[g] = pi * (CC_ - 1) + (c - 1);
                    cpidx[g] = p;
                }
            }
        }
    }
}

// ---------------------------------------------------------------------------
// Kernel 2: per-candidate box regression (FP64 dot) + strict-fp32 decode.
// One WAVE per candidate. Decode uses explicit _rn ops so no fma contraction
// deviates from the reference's separate mul/add rounding.
// ---------------------------------------------------------------------------
__global__ __launch_bounds__(256) void decode_cand(
    const float* __restrict__ A, const float* __restrict__ Wb,
    const float* __restrict__ bb, const float* __restrict__ props,
    const int* __restrict__ cnt, const int* __restrict__ clab,
    const int* __restrict__ cpidx,
    float* __restrict__ cs, float* __restrict__ cx1, float* __restrict__ cy1,
    float* __restrict__ cx2, float* __restrict__ cy2)
{
    const int wid = (blockIdx.x * 256 + threadIdx.x) >> 6;
    const int lane = threadIdx.x & 63;
    const int b = wid / CAP_;
    const int pos = wid - b * CAP_;
    if (b >= BB_) return;
    const int n = min(cnt[b], CAP_);
    if (pos >= n) return;

    const int g = b * CAP_ + pos;
    const int p = cpidx[g];
    const int c = clab[g];

    const float* fr = A + (size_t)p * FF_;
    const float* wb0 = Wb + 4 * c;

    double a0 = 0.0, a1 = 0.0, a2 = 0.0, a3 = 0.0;
    for (int k = lane; k < FF_; k += 64) {
        const double f = (double)fr[k];
        const float4 wv = *reinterpret_cast<const float4*>(wb0 + (size_t)k * (CC_ * 4));
        a0 += f * (double)wv.x; a1 += f * (double)wv.y;
        a2 += f * (double)wv.z; a3 += f * (double)wv.w;
    }
#pragma unroll
    for (int off = 32; off > 0; off >>= 1) {
        a0 += __shfl_xor(a0, off);
        a1 += __shfl_xor(a1, off);
        a2 += __shfl_xor(a2, off);
        a3 += __shfl_xor(a3, off);
    }

    if (lane == 0) {
        // deltas rounded to fp32 (+zero bias, fp32 add like ref)
        const float dx = __fadd_rn((float)a0, bb[4 * c + 0]);
        const float dy = __fadd_rn((float)a1, bb[4 * c + 1]);
        const float clipf = (float)BBOX_CLIP_D;
        const float dw = fminf(__fadd_rn((float)a2, bb[4 * c + 2]), clipf);
        const float dh = fminf(__fadd_rn((float)a3, bb[4 * c + 3]), clipf);

        const float px1 = props[(size_t)p * 4 + 0];
        const float py1 = props[(size_t)p * 4 + 1];
        const float px2 = props[(size_t)p * 4 + 2];
        const float py2 = props[(size_t)p * 4 + 3];
        const float w = __fsub_rn(px2, px1);
        const float h = __fsub_rn(py2, py1);
        const float cx = __fadd_rn(px1, __fmul_rn(0.5f, w));
        const float cy = __fadd_rn(py1, __fmul_rn(0.5f, h));

        const float pcx = __fadd_rn(__fmul_rn(dx, w), cx);
        const float pcy = __fadd_rn(__fmul_rn(dy, h), cy);
        const float ew = (float)exp((double)dw);   // ~correctly-rounded fp32 exp
        const float eh = (float)exp((double)dh);
        const float pw = __fmul_rn(ew, w);
        const float ph = __fmul_rn(eh, h);

        const float hw = __fmul_rn(0.5f, pw);
        const float hh = __fmul_rn(0.5f, ph);
        const float bx1 = fminf(fmaxf(__fsub_rn(pcx, hw), 0.f), IMG_W);
        const float by1 = fminf(fmaxf(__fsub_rn(pcy, hh), 0.f), IMG_H);
        const float bx2 = fminf(fmaxf(__fadd_rn(pcx, hw), 0.f), IMG_W);
        const float by2 = fminf(fmaxf(__fadd_rn(pcy, hh), 0.f), IMG_H);

        cx1[g] = bx1; cy1[g] = by1; cx2[g] = bx2; cy2[g] = by2;
        if (!(__fsub_rn(bx2, bx1) >= MIN_SZ && __fsub_rn(by2, by1) >= MIN_SZ)) {
            cs[g] = -INFINITY;   // fails keep-filter: never selectable
        }
    }
}

// ---------------------------------------------------------------------------
// Kernel 3: serial greedy NMS — one thread per image, literal reference.
// All fp32 ops are contraction-safe as written (mul-of-sub, l-to-r adds).
// ---------------------------------------------------------------------------
__global__ __launch_bounds__(64) void nms_serial(
    const float* __restrict__ c_x1, const float* __restrict__ c_y1,
    const float* __restrict__ c_x2, const float* __restrict__ c_y2,
    const float* __restrict__ c_s, const int* __restrict__ c_lab,
    const int* __restrict__ c_orig, const int* __restrict__ cnt,
    float* __restrict__ out)
{
    const int b = blockIdx.x;
    const int t = threadIdx.x;

    __shared__ float sx1[CAP_], sy1[CAP_], sx2[CAP_], sy2[CAP_], ss[CAP_];
    __shared__ int slab[CAP_], sorig[CAP_];

    const int n = min(cnt[b], CAP_);

    for (int i = t; i < n; i += 64) {
        const int g = b * CAP_ + i;
        sx1[i] = c_x1[g]; sy1[i] = c_y1[g];
        sx2[i] = c_x2[g]; sy2[i] = c_y2[g];
        ss[i] = c_s[g];
        slab[i] = c_lab[g]; sorig[i] = c_orig[g];
    }
    __syncthreads();

    if (t != 0) return;

    const int boxes_base = 0;
    const int scores_base = BB_ * DETS_ * 4;
    const int labels_base = BB_ * DETS_ * 5;

    int filled = 0;
    for (int it = 0; it < DETS_; ++it) {
        float bs = -INFINITY;
        int bi = -1;
        for (int i = 0; i < n; ++i) {
            const float s = ss[i];
            if (s == -INFINITY) continue;
            if (s > bs || (s == bs && (bi < 0 || sorig[i] < sorig[bi]))) {
                bs = s; bi = i;
            }
        }
        if (bi < 0 || !(bs > 0.f)) break;

        float* bo = out + boxes_base + (size_t)(b * DETS_ + it) * 4;
        bo[0] = sx1[bi]; bo[1] = sy1[bi]; bo[2] = sx2[bi]; bo[3] = sy2[bi];
        out[scores_base + b * DETS_ + it] = bs;
        out[labels_base + b * DETS_ + it] = (float)slab[bi];
        filled = it + 1;

        const int lj = slab[bi];
        const float off = __fmul_rn((float)lj, OFF_);
        const float ax1 = __fadd_rn(sx1[bi], off), ay1 = __fadd_rn(sy1[bi], off);
        const float ax2 = __fadd_rn(sx2[bi], off), ay2 = __fadd_rn(sy2[bi], off);
        const float a1 = __fmul_rn(__fsub_rn(ax2, ax1), __fsub_rn(ay2, ay1));
        for (int i = 0; i < n; ++i) {
            if (slab[i] != lj) continue;
            const float bx1 = __fadd_rn(sx1[i], off), by1 = __fadd_rn(sy1[i], off);
            const float bx2 = __fadd_rn(sx2[i], off), by2 = __fadd_rn(sy2[i], off);
            const float ix1 = fmaxf(ax1, bx1), iy1 = fmaxf(ay1, by1);
            const float ix2 = fminf(ax2, bx2), iy2 = fminf(ay2, by2);
            const float inter = __fmul_rn(fmaxf(__fsub_rn(ix2, ix1), 0.f),
                                          fmaxf(__fsub_rn(iy2, iy1), 0.f));
            const float a2 = __fmul_rn(__fsub_rn(bx2, bx1), __fsub_rn(by2, by1));
            const float den = __fadd_rn(__fsub_rn(__fadd_rn(a1, a2), inter), 1e-9f);
            const float iou = __fdiv_rn(inter, den);
            if (iou > NMS_TH) ss[i] = -INFINITY;
        }
    }
    for (int k = filled; k < DETS_; ++k) {
        float* bo = out + boxes_base + (size_t)(b * DETS_ + k) * 4;
        bo[0] = 0.f; bo[1] = 0.f; bo[2] = 0.f; bo[3] = 0.f;
        out[scores_base + b * DETS_ + k] = 0.f;
        out[labels_base + b * DETS_ + k] = 0.f;
    }
}

// ---------------------------------------------------------------------------
extern "C" void kernel_launch(void* const* d_in, const int* in_sizes, int n_in,
                              void* d_out, int out_size, void* d_ws, size_t ws_size,
                              hipStream_t stream)
{
    const float* feat  = (const float*)d_in[0];
    const float* Wc    = (const float*)d_in[1];
    const float* bc    = (const float*)d_in[2];
    const float* Wb    = (const float*)d_in[3];
    const float* bb    = (const float*)d_in[4];
    const float* props = (const float*)d_in[5];
    for (int i = 0; i < n_in; ++i) {
        const float* q = (const float*)d_in[i];
        switch (in_sizes[i]) {
            case 16384000: feat  = q; break;  // [16000,1024]
            case 93184:    Wc    = q; break;  // [1024,91]
            case 91:       bc    = q; break;
            case 372736:   Wb    = q; break;  // [1024,364]
            case 364:      bb    = q; break;
            case 64000:    props = q; break;  // [16,1000,4]
        }
    }
    float* out = (float*)d_out;

    char* ws = (char*)d_ws;
    int*   cnt   = (int*)ws;
    float* cs    = (float*)(ws + 256);
    int*   clab  = (int*)(cs + CAND_MAX);
    int*   corig = clab + CAND_MAX;
    int*   cpidx = corig + CAND_MAX;
    float* cx1   = (float*)(cpidx + CAND_MAX);
    float* cy1   = cx1 + CAND_MAX;
    float* cx2   = cy1 + CAND_MAX;
    float* cy2   = cx2 + CAND_MAX;

    hipMemsetAsync(cnt, 0, 64, stream);

    logits_cand<<<250, 256, 0, stream>>>(feat, Wc, bc,
        cs, clab, corig, cpidx, cnt);

    decode_cand<<<CAND_MAX / 4, 256, 0, stream>>>(feat, Wb, bb, props,
        cnt, clab, cpidx, cs, cx1, cy1, cx2, cy2);

    nms_serial<<<BB_, 64, 0, stream>>>(
        cx1, cy1, cx2, cy2, cs, clab, corig, cnt, out);
}

// Round 5
// 391.170 us; speedup vs baseline: 10.4943x; 10.4943x over previous
//
#include <hip/hip_runtime.h>
#include <hip/hip_bf16.h>
#include <math.h>

// Problem constants
#define BB_ 16          // images
#define PP_ 1000        // proposals per image
#define CC_ 91          // classes incl background
#define FF_ 1024        // feature dim
#define DETS_ 100
#define CAP_ 2048       // candidate capacity per image (expected ~320)
#define CAND_MAX (BB_ * CAP_)
#define IMG_W 800.0f
#define IMG_H 800.0f
#define OFF_ 802.0f     // max(H,W)+2
#define SCORE_TH 0.05f
#define NMS_TH 0.5f
#define MIN_SZ 0.01f
#define BBOX_CLIP_D 4.135166556742356   // log(1000/16)

// ---------------------------------------------------------------------------
// Kernel 1: logits GEMM in FP64 accumulation (64 rows x 91 cols per block),
// FP64 softmax, candidate selection. (unchanged from Round 4 — bit-exact)
// ---------------------------------------------------------------------------
__global__ __launch_bounds__(256) void logits_cand(
    const float* __restrict__ A, const float* __restrict__ Wc,
    const float* __restrict__ bc,
    float* __restrict__ cs, int* __restrict__ clab,
    int* __restrict__ corig, int* __restrict__ cpidx,
    int* __restrict__ cnt)
{
    __shared__ float As[16][65];   // [k][m]
    __shared__ float Bs[16][97];   // [k][n]
    __shared__ float Ssc[64][97];  // fp32 logits tile

    const int tid = threadIdx.x;
    const int row0 = blockIdx.x * 64;
    const int tx = tid & 15, ty = tid >> 4;
    const int ty4 = ty * 4, tx6 = tx * 6;

    const int am = tid >> 2;
    const int ak = (tid & 3) * 4;
    const int bk = tid >> 4;
    const int bn = (tid & 15) * 6;

    double acc[4][6];
#pragma unroll
    for (int i = 0; i < 4; ++i)
#pragma unroll
        for (int j = 0; j < 6; ++j) acc[i][j] = 0.0;

    for (int k0 = 0; k0 < FF_; k0 += 16) {
        const float4 av = *reinterpret_cast<const float4*>(
            A + (size_t)(row0 + am) * FF_ + k0 + ak);
        As[ak + 0][am] = av.x;
        As[ak + 1][am] = av.y;
        As[ak + 2][am] = av.z;
        As[ak + 3][am] = av.w;

        const int krow = k0 + bk;
#pragma unroll
        for (int jj = 0; jj < 6; ++jj) {
            const int c = bn + jj;
            Bs[bk][bn + jj] = (c < CC_) ? Wc[(size_t)krow * CC_ + c] : 0.f;
        }
        __syncthreads();

#pragma unroll
        for (int k = 0; k < 16; ++k) {
            float a[4], b[6];
#pragma unroll
            for (int i = 0; i < 4; ++i) a[i] = As[k][ty4 + i];
#pragma unroll
            for (int j = 0; j < 6; ++j) b[j] = Bs[k][tx6 + j];
#pragma unroll
            for (int i = 0; i < 4; ++i)
#pragma unroll
                for (int j = 0; j < 6; ++j)
                    acc[i][j] += (double)a[i] * (double)b[j];
        }
        __syncthreads();
    }

#pragma unroll
    for (int i = 0; i < 4; ++i)
#pragma unroll
        for (int j = 0; j < 6; ++j) {
            const int c = tx6 + j;
            if (c < CC_) {
                const float lf = (float)acc[i][j];
                Ssc[ty4 + i][c] = __fadd_rn(lf, bc[c]);
            }
        }
    __syncthreads();

    if (tid < 64) {
        const int p = row0 + tid;
        const int b = p / PP_;
        const int pi = p - b * PP_;

        float m = Ssc[tid][0];
        for (int c = 1; c < CC_; ++c) m = fmaxf(m, Ssc[tid][c]);
        double denom = 0.0;
        for (int c = 0; c < CC_; ++c)
            denom += exp((double)Ssc[tid][c] - (double)m);

        for (int c = 1; c < CC_; ++c) {
            const double sd = exp((double)Ssc[tid][c] - (double)m) / denom;
            const float score = (float)sd;
            if (score > SCORE_TH) {
                const int pos = atomicAdd(&cnt[b], 1);
                if (pos < CAP_) {
                    const int g = b * CAP_ + pos;
                    cs[g] = score;
                    clab[g] = c;
                    corig[g] = pi * (CC_ - 1) + (c - 1);
                    cpidx[g] = p;
                }
            }
        }
    }
}

// ---------------------------------------------------------------------------
// Kernel 2: per-candidate box regression (FP64 dot) + strict-fp32 decode.
// (unchanged from Round 4 — bit-exact)
// ---------------------------------------------------------------------------
__global__ __launch_bounds__(256) void decode_cand(
    const float* __restrict__ A, const float* __restrict__ Wb,
    const float* __restrict__ bb, const float* __restrict__ props,
    const int* __restrict__ cnt, const int* __restrict__ clab,
    const int* __restrict__ cpidx,
    float* __restrict__ cs, float* __restrict__ cx1, float* __restrict__ cy1,
    float* __restrict__ cx2, float* __restrict__ cy2)
{
    const int wid = (blockIdx.x * 256 + threadIdx.x) >> 6;
    const int lane = threadIdx.x & 63;
    const int b = wid / CAP_;
    const int pos = wid - b * CAP_;
    if (b >= BB_) return;
    const int n = min(cnt[b], CAP_);
    if (pos >= n) return;

    const int g = b * CAP_ + pos;
    const int p = cpidx[g];
    const int c = clab[g];

    const float* fr = A + (size_t)p * FF_;
    const float* wb0 = Wb + 4 * c;

    double a0 = 0.0, a1 = 0.0, a2 = 0.0, a3 = 0.0;
    for (int k = lane; k < FF_; k += 64) {
        const double f = (double)fr[k];
        const float4 wv = *reinterpret_cast<const float4*>(wb0 + (size_t)k * (CC_ * 4));
        a0 += f * (double)wv.x; a1 += f * (double)wv.y;
        a2 += f * (double)wv.z; a3 += f * (double)wv.w;
    }
#pragma unroll
    for (int off = 32; off > 0; off >>= 1) {
        a0 += __shfl_xor(a0, off);
        a1 += __shfl_xor(a1, off);
        a2 += __shfl_xor(a2, off);
        a3 += __shfl_xor(a3, off);
    }

    if (lane == 0) {
        const float dx = __fadd_rn((float)a0, bb[4 * c + 0]);
        const float dy = __fadd_rn((float)a1, bb[4 * c + 1]);
        const float clipf = (float)BBOX_CLIP_D;
        const float dw = fminf(__fadd_rn((float)a2, bb[4 * c + 2]), clipf);
        const float dh = fminf(__fadd_rn((float)a3, bb[4 * c + 3]), clipf);

        const float px1 = props[(size_t)p * 4 + 0];
        const float py1 = props[(size_t)p * 4 + 1];
        const float px2 = props[(size_t)p * 4 + 2];
        const float py2 = props[(size_t)p * 4 + 3];
        const float w = __fsub_rn(px2, px1);
        const float h = __fsub_rn(py2, py1);
        const float cx = __fadd_rn(px1, __fmul_rn(0.5f, w));
        const float cy = __fadd_rn(py1, __fmul_rn(0.5f, h));

        const float pcx = __fadd_rn(__fmul_rn(dx, w), cx);
        const float pcy = __fadd_rn(__fmul_rn(dy, h), cy);
        const float ew = (float)exp((double)dw);
        const float eh = (float)exp((double)dh);
        const float pw = __fmul_rn(ew, w);
        const float ph = __fmul_rn(eh, h);

        const float hw = __fmul_rn(0.5f, pw);
        const float hh = __fmul_rn(0.5f, ph);
        const float bx1 = fminf(fmaxf(__fsub_rn(pcx, hw), 0.f), IMG_W);
        const float by1 = fminf(fmaxf(__fsub_rn(pcy, hh), 0.f), IMG_H);
        const float bx2 = fminf(fmaxf(__fadd_rn(pcx, hw), 0.f), IMG_W);
        const float by2 = fminf(fmaxf(__fadd_rn(pcy, hh), 0.f), IMG_H);

        cx1[g] = bx1; cy1[g] = by1; cx2[g] = bx2; cy2[g] = by2;
        if (!(__fsub_rn(bx2, bx1) >= MIN_SZ && __fsub_rn(by2, by1) >= MIN_SZ)) {
            cs[g] = -INFINITY;
        }
    }
}

// ---------------------------------------------------------------------------
// Kernel 3: PARALLEL greedy NMS — one block (256 thr) per image.
// Argmax via packed u64 key (score_bits<<32 | ~sorig): exact max-score with
// lowest-original-index tie-break; bit-identical selection to the serial ref.
// Suppression arithmetic unchanged (strict _rn fp32).
// ---------------------------------------------------------------------------
__global__ __launch_bounds__(256) void nms_parallel(
    const float* __restrict__ c_x1, const float* __restrict__ c_y1,
    const float* __restrict__ c_x2, const float* __restrict__ c_y2,
    const float* __restrict__ c_s, const int* __restrict__ c_lab,
    const int* __restrict__ c_orig, const int* __restrict__ cnt,
    float* __restrict__ out)
{
    const int b = blockIdx.x;
    const int t = threadIdx.x;
    const int lane = t & 63;
    const int wv = t >> 6;

    __shared__ float sx1[CAP_], sy1[CAP_], sx2[CAP_], sy2[CAP_], ss[CAP_];
    __shared__ int slab[CAP_], sorig[CAP_];
    __shared__ unsigned long long rk[4];
    __shared__ int winner;

    const int n = min(cnt[b], CAP_);

    for (int i = t; i < n; i += 256) {
        const int g = b * CAP_ + i;
        sx1[i] = c_x1[g]; sy1[i] = c_y1[g];
        sx2[i] = c_x2[g]; sy2[i] = c_y2[g];
        ss[i] = c_s[g];
        slab[i] = c_lab[g]; sorig[i] = c_orig[g];
    }
    __syncthreads();

    const int boxes_base = 0;
    const int scores_base = BB_ * DETS_ * 4;
    const int labels_base = BB_ * DETS_ * 5;

    for (int it = 0; it < DETS_; ++it) {
        // --- exact argmax via packed key ---
        unsigned long long best = 0ull;
        for (int i = t; i < n; i += 256) {
            const float s = ss[i];
            if (s > 0.f) {
                const unsigned long long key =
                    ((unsigned long long)__float_as_uint(s) << 32) |
                    (unsigned int)(0x7FFFFFFF - sorig[i]);
                best = (key > best) ? key : best;
            }
        }
#pragma unroll
        for (int off = 32; off > 0; off >>= 1) {
            const unsigned long long o = __shfl_xor(best, off);
            best = (o > best) ? o : best;
        }
        if (lane == 0) rk[wv] = best;
        __syncthreads();
        if (t == 0) {
            unsigned long long m01 = (rk[0] > rk[1]) ? rk[0] : rk[1];
            unsigned long long m23 = (rk[2] > rk[3]) ? rk[2] : rk[3];
            rk[0] = (m01 > m23) ? m01 : m23;
        }
        __syncthreads();
        best = rk[0];

        if (best == 0ull) {
            // all remaining are suppressed: zero-fill the tail, done
            for (int k = it + t; k < DETS_; k += 256) {
                float* bo = out + boxes_base + (size_t)(b * DETS_ + k) * 4;
                bo[0] = 0.f; bo[1] = 0.f; bo[2] = 0.f; bo[3] = 0.f;
                out[scores_base + b * DETS_ + k] = 0.f;
                out[labels_base + b * DETS_ + k] = 0.f;
            }
            break;
        }

        // locate winner (key is unique: sorig unique per candidate)
        for (int i = t; i < n; i += 256) {
            const float s = ss[i];
            if (s > 0.f) {
                const unsigned long long key =
                    ((unsigned long long)__float_as_uint(s) << 32) |
                    (unsigned int)(0x7FFFFFFF - sorig[i]);
                if (key == best) winner = i;
            }
        }
        __syncthreads();
        const int j = winner;
        const int lj = slab[j];

        if (t == 0) {
            float* bo = out + boxes_base + (size_t)(b * DETS_ + it) * 4;
            bo[0] = sx1[j]; bo[1] = sy1[j]; bo[2] = sx2[j]; bo[3] = sy2[j];
            out[scores_base + b * DETS_ + it] = ss[j];
            out[labels_base + b * DETS_ + it] = (float)lj;
        }

        // --- suppression (strict fp32, same bits as serial version) ---
        const float off = __fmul_rn((float)lj, OFF_);
        const float ax1 = __fadd_rn(sx1[j], off), ay1 = __fadd_rn(sy1[j], off);
        const float ax2 = __fadd_rn(sx2[j], off), ay2 = __fadd_rn(sy2[j], off);
        const float a1 = __fmul_rn(__fsub_rn(ax2, ax1), __fsub_rn(ay2, ay1));
        __syncthreads();   // winner/ss reads done before writes
        for (int i = t; i < n; i += 256) {
            if (slab[i] != lj) continue;
            const float bx1 = __fadd_rn(sx1[i], off), by1 = __fadd_rn(sy1[i], off);
            const float bx2 = __fadd_rn(sx2[i], off), by2 = __fadd_rn(sy2[i], off);
            const float ix1 = fmaxf(ax1, bx1), iy1 = fmaxf(ay1, by1);
            const float ix2 = fminf(ax2, bx2), iy2 = fminf(ay2, by2);
            const float inter = __fmul_rn(fmaxf(__fsub_rn(ix2, ix1), 0.f),
                                          fmaxf(__fsub_rn(iy2, iy1), 0.f));
            const float a2 = __fmul_rn(__fsub_rn(bx2, bx1), __fsub_rn(by2, by1));
            const float den = __fadd_rn(__fsub_rn(__fadd_rn(a1, a2), inter), 1e-9f);
            const float iou = __fdiv_rn(inter, den);
            if (iou > NMS_TH) ss[i] = -INFINITY;   // includes j itself (iou=1)
        }
        __syncthreads();
    }
}

// ---------------------------------------------------------------------------
extern "C" void kernel_launch(void* const* d_in, const int* in_sizes, int n_in,
                              void* d_out, int out_size, void* d_ws, size_t ws_size,
                              hipStream_t stream)
{
    const float* feat  = (const float*)d_in[0];
    const float* Wc    = (const float*)d_in[1];
    const float* bc    = (const float*)d_in[2];
    const float* Wb    = (const float*)d_in[3];
    const float* bb    = (const float*)d_in[4];
    const float* props = (const float*)d_in[5];
    for (int i = 0; i < n_in; ++i) {
        const float* q = (const float*)d_in[i];
        switch (in_sizes[i]) {
            case 16384000: feat  = q; break;  // [16000,1024]
            case 93184:    Wc    = q; break;  // [1024,91]
            case 91:       bc    = q; break;
            case 372736:   Wb    = q; break;  // [1024,364]
            case 364:      bb    = q; break;
            case 64000:    props = q; break;  // [16,1000,4]
        }
    }
    float* out = (float*)d_out;

    char* ws = (char*)d_ws;
    int*   cnt   = (int*)ws;
    float* cs    = (float*)(ws + 256);
    int*   clab  = (int*)(cs + CAND_MAX);
    int*   corig = clab + CAND_MAX;
    int*   cpidx = corig + CAND_MAX;
    float* cx1   = (float*)(cpidx + CAND_MAX);
    float* cy1   = cx1 + CAND_MAX;
    float* cx2   = cy1 + CAND_MAX;
    float* cy2   = cx2 + CAND_MAX;

    hipMemsetAsync(cnt, 0, 64, stream);

    logits_cand<<<250, 256, 0, stream>>>(feat, Wc, bc,
        cs, clab, corig, cpidx, cnt);

    decode_cand<<<CAND_MAX / 4, 256, 0, stream>>>(feat, Wb, bb, props,
        cnt, clab, cpidx, cs, cx1, cy1, cx2, cy2);

    nms_parallel<<<BB_, 256, 0, stream>>>(
        cx1, cy1, cx2, cy2, cs, clab, corig, cnt, out);
}

// Round 6
// 342.840 us; speedup vs baseline: 11.9737x; 1.1410x over previous
//
#include <hip/hip_runtime.h>
#include <hip/hip_bf16.h>
#include <math.h>

// Problem constants
#define BB_ 16          // images
#define PP_ 1000        // proposals per image
#define CC_ 91          // classes incl background
#define FF_ 1024        // feature dim
#define DETS_ 100
#define CAP_ 2048       // candidate capacity per image (expected ~320)
#define CAND_MAX (BB_ * CAP_)
#define IMG_W 800.0f
#define IMG_H 800.0f
#define OFF_ 802.0f     // max(H,W)+2
#define SCORE_TH 0.05f
#define NMS_TH 0.5f
#define MIN_SZ 0.01f
#define BBOX_CLIP_D 4.135166556742356   // log(1000/16)

// ---------------------------------------------------------------------------
// Kernel 1: logits GEMM, FP64 accumulation. 32 rows x 91 cols per block ->
// 500 blocks (~2/CU, 2 waves/SIMD) for latency hiding; reg-prefetch of next
// tile. Numerics: strictly-sequential fp64 K-accumulation — bit-identical to
// the passing Round-4/5 kernel.
// ---------------------------------------------------------------------------
__global__ __launch_bounds__(256) void logits_cand(
    const float* __restrict__ A, const float* __restrict__ Wc,
    const float* __restrict__ bc,
    float* __restrict__ cs, int* __restrict__ clab,
    int* __restrict__ corig, int* __restrict__ cpidx,
    int* __restrict__ cnt)
{
    __shared__ float As[16][34];   // [k][m], pad 34 -> float2-aligned reads
    __shared__ float Bs[16][98];   // [k][n], pad 98 -> float2-aligned reads
    __shared__ float Ssc[32][97];  // fp32 logits tile (odd stride: no conflict)

    const int tid = threadIdx.x;
    const int row0 = blockIdx.x * 32;
    const int tx = tid & 15, ty = tid >> 4;
    const int ty2 = ty * 2, tx6 = tx * 6;

    // A-load mapping (threads 0..127): 32 rows x 16 k, float4 each
    const int am = tid >> 2;         // row 0..31
    const int ak = (tid & 3) * 4;    // k subcol
    // B-load mapping (all 256): 16 k x 96 cols, 6 scalars each
    const int bk = tid >> 4;
    const int bn = (tid & 15) * 6;

    double acc[2][6];
#pragma unroll
    for (int i = 0; i < 2; ++i)
#pragma unroll
        for (int j = 0; j < 6; ++j) acc[i][j] = 0.0;

    // prologue prefetch (k0 = 0)
    float4 avP = make_float4(0.f, 0.f, 0.f, 0.f);
    if (tid < 128)
        avP = *reinterpret_cast<const float4*>(A + (size_t)(row0 + am) * FF_ + ak);
    float bvP[6];
#pragma unroll
    for (int jj = 0; jj < 6; ++jj) {
        const int c = bn + jj;
        bvP[jj] = (c < CC_) ? Wc[(size_t)bk * CC_ + c] : 0.f;
    }

    for (int k0 = 0; k0 < FF_; k0 += 16) {
        // stage current tile
        if (tid < 128) {
            As[ak + 0][am] = avP.x;
            As[ak + 1][am] = avP.y;
            As[ak + 2][am] = avP.z;
            As[ak + 3][am] = avP.w;
        }
#pragma unroll
        for (int jj = 0; jj < 6; ++jj) Bs[bk][bn + jj] = bvP[jj];

        // issue next-tile prefetch (in flight during compute)
        const int kn = k0 + 16;
        if (kn < FF_) {
            if (tid < 128)
                avP = *reinterpret_cast<const float4*>(
                    A + (size_t)(row0 + am) * FF_ + kn + ak);
#pragma unroll
            for (int jj = 0; jj < 6; ++jj) {
                const int c = bn + jj;
                bvP[jj] = (c < CC_) ? Wc[(size_t)(kn + bk) * CC_ + c] : 0.f;
            }
        }
        __syncthreads();

#pragma unroll
        for (int k = 0; k < 16; ++k) {
            const float2 a01 = *reinterpret_cast<const float2*>(&As[k][ty2]);
            const float2 b01 = *reinterpret_cast<const float2*>(&Bs[k][tx6 + 0]);
            const float2 b23 = *reinterpret_cast<const float2*>(&Bs[k][tx6 + 2]);
            const float2 b45 = *reinterpret_cast<const float2*>(&Bs[k][tx6 + 4]);
            const double a0 = (double)a01.x, a1 = (double)a01.y;
            const double b0 = (double)b01.x, b1 = (double)b01.y;
            const double b2 = (double)b23.x, b3 = (double)b23.y;
            const double b4 = (double)b45.x, b5 = (double)b45.y;
            acc[0][0] += a0 * b0; acc[0][1] += a0 * b1; acc[0][2] += a0 * b2;
            acc[0][3] += a0 * b3; acc[0][4] += a0 * b4; acc[0][5] += a0 * b5;
            acc[1][0] += a1 * b0; acc[1][1] += a1 * b1; acc[1][2] += a1 * b2;
            acc[1][3] += a1 * b3; acc[1][4] += a1 * b4; acc[1][5] += a1 * b5;
        }
        __syncthreads();
    }

    // fp32 logits (+bias) into LDS
#pragma unroll
    for (int i = 0; i < 2; ++i)
#pragma unroll
        for (int j = 0; j < 6; ++j) {
            const int c = tx6 + j;
            if (c < CC_) {
                const float lf = (float)acc[i][j];
                Ssc[ty2 + i][c] = __fadd_rn(lf, bc[c]);
            }
        }
    __syncthreads();

    // per-row fp64 softmax + threshold; threads 0..31 (one row each)
    if (tid < 32) {
        const int p = row0 + tid;
        const int b = p / PP_;
        const int pi = p - b * PP_;

        float m = Ssc[tid][0];
        for (int c = 1; c < CC_; ++c) m = fmaxf(m, Ssc[tid][c]);
        double denom = 0.0;
        for (int c = 0; c < CC_; ++c)
            denom += exp((double)Ssc[tid][c] - (double)m);

        for (int c = 1; c < CC_; ++c) {
            const double sd = exp((double)Ssc[tid][c] - (double)m) / denom;
            const float score = (float)sd;
            if (score > SCORE_TH) {
                const int pos = atomicAdd(&cnt[b], 1);
                if (pos < CAP_) {
                    const int g = b * CAP_ + pos;
                    cs[g] = score;
                    clab[g] = c;
                    corig[g] = pi * (CC_ - 1) + (c - 1);
                    cpidx[g] = p;
                }
            }
        }
    }
}

// ---------------------------------------------------------------------------
// Kernel 2: per-candidate box regression (FP64 dot) + strict-fp32 decode.
// (unchanged — bit-exact)
// ---------------------------------------------------------------------------
__global__ __launch_bounds__(256) void decode_cand(
    const float* __restrict__ A, const float* __restrict__ Wb,
    const float* __restrict__ bb, const float* __restrict__ props,
    const int* __restrict__ cnt, const int* __restrict__ clab,
    const int* __restrict__ cpidx,
    float* __restrict__ cs, float* __restrict__ cx1, float* __restrict__ cy1,
    float* __restrict__ cx2, float* __restrict__ cy2)
{
    const int wid = (blockIdx.x * 256 + threadIdx.x) >> 6;
    const int lane = threadIdx.x & 63;
    const int b = wid / CAP_;
    const int pos = wid - b * CAP_;
    if (b >= BB_) return;
    const int n = min(cnt[b], CAP_);
    if (pos >= n) return;

    const int g = b * CAP_ + pos;
    const int p = cpidx[g];
    const int c = clab[g];

    const float* fr = A + (size_t)p * FF_;
    const float* wb0 = Wb + 4 * c;

    double a0 = 0.0, a1 = 0.0, a2 = 0.0, a3 = 0.0;
    for (int k = lane; k < FF_; k += 64) {
        const double f = (double)fr[k];
        const float4 wv = *reinterpret_cast<const float4*>(wb0 + (size_t)k * (CC_ * 4));
        a0 += f * (double)wv.x; a1 += f * (double)wv.y;
        a2 += f * (double)wv.z; a3 += f * (double)wv.w;
    }
#pragma unroll
    for (int off = 32; off > 0; off >>= 1) {
        a0 += __shfl_xor(a0, off);
        a1 += __shfl_xor(a1, off);
        a2 += __shfl_xor(a2, off);
        a3 += __shfl_xor(a3, off);
    }

    if (lane == 0) {
        const float dx = __fadd_rn((float)a0, bb[4 * c + 0]);
        const float dy = __fadd_rn((float)a1, bb[4 * c + 1]);
        const float clipf = (float)BBOX_CLIP_D;
        const float dw = fminf(__fadd_rn((float)a2, bb[4 * c + 2]), clipf);
        const float dh = fminf(__fadd_rn((float)a3, bb[4 * c + 3]), clipf);

        const float px1 = props[(size_t)p * 4 + 0];
        const float py1 = props[(size_t)p * 4 + 1];
        const float px2 = props[(size_t)p * 4 + 2];
        const float py2 = props[(size_t)p * 4 + 3];
        const float w = __fsub_rn(px2, px1);
        const float h = __fsub_rn(py2, py1);
        const float cx = __fadd_rn(px1, __fmul_rn(0.5f, w));
        const float cy = __fadd_rn(py1, __fmul_rn(0.5f, h));

        const float pcx = __fadd_rn(__fmul_rn(dx, w), cx);
        const float pcy = __fadd_rn(__fmul_rn(dy, h), cy);
        const float ew = (float)exp((double)dw);
        const float eh = (float)exp((double)dh);
        const float pw = __fmul_rn(ew, w);
        const float ph = __fmul_rn(eh, h);

        const float hw = __fmul_rn(0.5f, pw);
        const float hh = __fmul_rn(0.5f, ph);
        const float bx1 = fminf(fmaxf(__fsub_rn(pcx, hw), 0.f), IMG_W);
        const float by1 = fminf(fmaxf(__fsub_rn(pcy, hh), 0.f), IMG_H);
        const float bx2 = fminf(fmaxf(__fadd_rn(pcx, hw), 0.f), IMG_W);
        const float by2 = fminf(fmaxf(__fadd_rn(pcy, hh), 0.f), IMG_H);

        cx1[g] = bx1; cy1[g] = by1; cx2[g] = bx2; cy2[g] = by2;
        if (!(__fsub_rn(bx2, bx1) >= MIN_SZ && __fsub_rn(by2, by1) >= MIN_SZ)) {
            cs[g] = -INFINITY;
        }
    }
}

// ---------------------------------------------------------------------------
// Kernel 3: PARALLEL greedy NMS — one block (256 thr) per image.
// (unchanged — bit-exact)
// ---------------------------------------------------------------------------
__global__ __launch_bounds__(256) void nms_parallel(
    const float* __restrict__ c_x1, const float* __restrict__ c_y1,
    const float* __restrict__ c_x2, const float* __restrict__ c_y2,
    const float* __restrict__ c_s, const int* __restrict__ c_lab,
    const int* __restrict__ c_orig, const int* __restrict__ cnt,
    float* __restrict__ out)
{
    const int b = blockIdx.x;
    const int t = threadIdx.x;
    const int lane = t & 63;
    const int wv = t >> 6;

    __shared__ float sx1[CAP_], sy1[CAP_], sx2[CAP_], sy2[CAP_], ss[CAP_];
    __shared__ int slab[CAP_], sorig[CAP_];
    __shared__ unsigned long long rk[4];
    __shared__ int winner;

    const int n = min(cnt[b], CAP_);

    for (int i = t; i < n; i += 256) {
        const int g = b * CAP_ + i;
        sx1[i] = c_x1[g]; sy1[i] = c_y1[g];
        sx2[i] = c_x2[g]; sy2[i] = c_y2[g];
        ss[i] = c_s[g];
        slab[i] = c_lab[g]; sorig[i] = c_orig[g];
    }
    __syncthreads();

    const int boxes_base = 0;
    const int scores_base = BB_ * DETS_ * 4;
    const int labels_base = BB_ * DETS_ * 5;

    for (int it = 0; it < DETS_; ++it) {
        unsigned long long best = 0ull;
        for (int i = t; i < n; i += 256) {
            const float s = ss[i];
            if (s > 0.f) {
                const unsigned long long key =
                    ((unsigned long long)__float_as_uint(s) << 32) |
                    (unsigned int)(0x7FFFFFFF - sorig[i]);
                best = (key > best) ? key : best;
            }
        }
#pragma unroll
        for (int off = 32; off > 0; off >>= 1) {
            const unsigned long long o = __shfl_xor(best, off);
            best = (o > best) ? o : best;
        }
        if (lane == 0) rk[wv] = best;
        __syncthreads();
        if (t == 0) {
            unsigned long long m01 = (rk[0] > rk[1]) ? rk[0] : rk[1];
            unsigned long long m23 = (rk[2] > rk[3]) ? rk[2] : rk[3];
            rk[0] = (m01 > m23) ? m01 : m23;
        }
        __syncthreads();
        best = rk[0];

        if (best == 0ull) {
            for (int k = it + t; k < DETS_; k += 256) {
                float* bo = out + boxes_base + (size_t)(b * DETS_ + k) * 4;
                bo[0] = 0.f; bo[1] = 0.f; bo[2] = 0.f; bo[3] = 0.f;
                out[scores_base + b * DETS_ + k] = 0.f;
                out[labels_base + b * DETS_ + k] = 0.f;
            }
            break;
        }

        for (int i = t; i < n; i += 256) {
            const float s = ss[i];
            if (s > 0.f) {
                const unsigned long long key =
                    ((unsigned long long)__float_as_uint(s) << 32) |
                    (unsigned int)(0x7FFFFFFF - sorig[i]);
                if (key == best) winner = i;
            }
        }
        __syncthreads();
        const int j = winner;
        const int lj = slab[j];

        if (t == 0) {
            float* bo = out + boxes_base + (size_t)(b * DETS_ + it) * 4;
            bo[0] = sx1[j]; bo[1] = sy1[j]; bo[2] = sx2[j]; bo[3] = sy2[j];
            out[scores_base + b * DETS_ + it] = ss[j];
            out[labels_base + b * DETS_ + it] = (float)lj;
        }

        const float off = __fmul_rn((float)lj, OFF_);
        const float ax1 = __fadd_rn(sx1[j], off), ay1 = __fadd_rn(sy1[j], off);
        const float ax2 = __fadd_rn(sx2[j], off), ay2 = __fadd_rn(sy2[j], off);
        const float a1 = __fmul_rn(__fsub_rn(ax2, ax1), __fsub_rn(ay2, ay1));
        __syncthreads();
        for (int i = t; i < n; i += 256) {
            if (slab[i] != lj) continue;
            const float bx1 = __fadd_rn(sx1[i], off), by1 = __fadd_rn(sy1[i], off);
            const float bx2 = __fadd_rn(sx2[i], off), by2 = __fadd_rn(sy2[i], off);
            const float ix1 = fmaxf(ax1, bx1), iy1 = fmaxf(ay1, by1);
            const float ix2 = fminf(ax2, bx2), iy2 = fminf(ay2, by2);
            const float inter = __fmul_rn(fmaxf(__fsub_rn(ix2, ix1), 0.f),
                                          fmaxf(__fsub_rn(iy2, iy1), 0.f));
            const float a2 = __fmul_rn(__fsub_rn(bx2, bx1), __fsub_rn(by2, by1));
            const float den = __fadd_rn(__fsub_rn(__fadd_rn(a1, a2), inter), 1e-9f);
            const float iou = __fdiv_rn(inter, den);
            if (iou > NMS_TH) ss[i] = -INFINITY;
        }
        __syncthreads();
    }
}

// ---------------------------------------------------------------------------
extern "C" void kernel_launch(void* const* d_in, const int* in_sizes, int n_in,
                              void* d_out, int out_size, void* d_ws, size_t ws_size,
                              hipStream_t stream)
{
    const float* feat  = (const float*)d_in[0];
    const float* Wc    = (const float*)d_in[1];
    const float* bc    = (const float*)d_in[2];
    const float* Wb    = (const float*)d_in[3];
    const float* bb    = (const float*)d_in[4];
    const float* props = (const float*)d_in[5];
    for (int i = 0; i < n_in; ++i) {
        const float* q = (const float*)d_in[i];
        switch (in_sizes[i]) {
            case 16384000: feat  = q; break;  // [16000,1024]
            case 93184:    Wc    = q; break;  // [1024,91]
            case 91:       bc    = q; break;
            case 372736:   Wb    = q; break;  // [1024,364]
            case 364:      bb    = q; break;
            case 64000:    props = q; break;  // [16,1000,4]
        }
    }
    float* out = (float*)d_out;

    char* ws = (char*)d_ws;
    int*   cnt   = (int*)ws;
    float* cs    = (float*)(ws + 256);
    int*   clab  = (int*)(cs + CAND_MAX);
    int*   corig = clab + CAND_MAX;
    int*   cpidx = corig + CAND_MAX;
    float* cx1   = (float*)(cpidx + CAND_MAX);
    float* cy1   = cx1 + CAND_MAX;
    float* cx2   = cy1 + CAND_MAX;
    float* cy2   = cx2 + CAND_MAX;

    hipMemsetAsync(cnt, 0, 64, stream);

    logits_cand<<<500, 256, 0, stream>>>(feat, Wc, bc,
        cs, clab, corig, cpidx, cnt);

    decode_cand<<<CAND_MAX / 4, 256, 0, stream>>>(feat, Wb, bb, props,
        cnt, clab, cpidx, cs, cx1, cy1, cx2, cy2);

    nms_parallel<<<BB_, 256, 0, stream>>>(
        cx1, cy1, cx2, cy2, cs, clab, corig, cnt, out);
}

// Round 7
// 295.802 us; speedup vs baseline: 13.8778x; 1.1590x over previous
//
#include <hip/hip_runtime.h>
#include <hip/hip_bf16.h>
#include <math.h>

typedef unsigned long long ull;

// Problem constants
#define BB_ 16          // images
#define PP_ 1000        // proposals per image
#define CC_ 91          // classes incl background
#define FF_ 1024        // feature dim
#define DETS_ 100
#define CAP_ 2048       // candidate capacity per image (measured ~320)
#define CAND_MAX (BB_ * CAP_)
#define SURV_CAP 2048   // NMS-survivor capacity per image
#define CLS_CAP 256     // per-(image,class) candidate capacity (measured ~<20)
#define IMG_W 800.0f
#define IMG_H 800.0f
#define OFF_ 802.0f     // max(H,W)+2
#define SCORE_TH 0.05f
#define NMS_TH 0.5f
#define MIN_SZ 0.01f
#define BBOX_CLIP_D 4.135166556742356   // log(1000/16)

// ---------------------------------------------------------------------------
// Kernel 1: logits GEMM, FP64 accumulation, LDS tiles stored as DOUBLE
// (single convert at staging). 32 rows x 96 cols per block, 256 threads,
// per-thread 4 rows x 3 cols = 12 fp64 FMA per k-step, zero inner converts.
// K-accumulation strictly sequential per output -> bit-identical scores.
// ---------------------------------------------------------------------------
__global__ __launch_bounds__(256) void logits_cand(
    const float* __restrict__ A, const float* __restrict__ Wc,
    const float* __restrict__ bc,
    float* __restrict__ cs, int* __restrict__ clab,
    int* __restrict__ corig, int* __restrict__ cpidx,
    int* __restrict__ cnt)
{
    __shared__ union SM {
        struct { double Ad[16][34]; double Bd[16][98]; } t;  // GEMM tiles
        float Ssc[32][97];                                   // logits (reuse)
    } sm;

    const int tid = threadIdx.x;
    const int row0 = blockIdx.x * 32;
    const int tx = tid & 31;       // 0..31 -> 3 cols each
    const int ty = tid >> 5;       // 0..7  -> 4 rows each
    const int tx3 = tx * 3, ty4 = ty * 4;

    // A staging map (tid<128): 32 rows x 16 k via float4
    const int am = tid >> 2;
    const int ak = (tid & 3) * 4;
    // B staging map (all 256): 16 k x 96 cols, 6 floats each
    const int bk = tid >> 4;
    const int bn = (tid & 15) * 6;

    double acc[4][3];
#pragma unroll
    for (int i = 0; i < 4; ++i)
#pragma unroll
        for (int j = 0; j < 3; ++j) acc[i][j] = 0.0;

    // prologue prefetch (k0 = 0)
    float4 avP = make_float4(0.f, 0.f, 0.f, 0.f);
    if (tid < 128)
        avP = *reinterpret_cast<const float4*>(A + (size_t)(row0 + am) * FF_ + ak);
    float bvP[6];
#pragma unroll
    for (int jj = 0; jj < 6; ++jj) {
        const int c = bn + jj;
        bvP[jj] = (c < CC_) ? Wc[(size_t)bk * CC_ + c] : 0.f;
    }

    for (int k0 = 0; k0 < FF_; k0 += 16) {
        // stage current tile (convert to double ONCE here)
        if (tid < 128) {
            sm.t.Ad[ak + 0][am] = (double)avP.x;
            sm.t.Ad[ak + 1][am] = (double)avP.y;
            sm.t.Ad[ak + 2][am] = (double)avP.z;
            sm.t.Ad[ak + 3][am] = (double)avP.w;
        }
#pragma unroll
        for (int jj = 0; jj < 6; ++jj) sm.t.Bd[bk][bn + jj] = (double)bvP[jj];

        // prefetch next tile
        const int kn = k0 + 16;
        if (kn < FF_) {
            if (tid < 128)
                avP = *reinterpret_cast<const float4*>(
                    A + (size_t)(row0 + am) * FF_ + kn + ak);
#pragma unroll
            for (int jj = 0; jj < 6; ++jj) {
                const int c = bn + jj;
                bvP[jj] = (c < CC_) ? Wc[(size_t)(kn + bk) * CC_ + c] : 0.f;
            }
        }
        __syncthreads();

#pragma unroll
        for (int k = 0; k < 16; ++k) {
            const double a0 = sm.t.Ad[k][ty4 + 0];
            const double a1 = sm.t.Ad[k][ty4 + 1];
            const double a2 = sm.t.Ad[k][ty4 + 2];
            const double a3 = sm.t.Ad[k][ty4 + 3];
            const double b0 = sm.t.Bd[k][tx3 + 0];
            const double b1 = sm.t.Bd[k][tx3 + 1];
            const double b2 = sm.t.Bd[k][tx3 + 2];
            acc[0][0] += a0 * b0; acc[0][1] += a0 * b1; acc[0][2] += a0 * b2;
            acc[1][0] += a1 * b0; acc[1][1] += a1 * b1; acc[1][2] += a1 * b2;
            acc[2][0] += a2 * b0; acc[2][1] += a2 * b1; acc[2][2] += a2 * b2;
            acc[3][0] += a3 * b0; acc[3][1] += a3 * b1; acc[3][2] += a3 * b2;
        }
        __syncthreads();
    }

    // fp32 logits (+bias) into LDS (tiles dead past this barrier-pair)
#pragma unroll
    for (int i = 0; i < 4; ++i)
#pragma unroll
        for (int j = 0; j < 3; ++j) {
            const int c = tx3 + j;
            if (c < CC_) {
                const float lf = (float)acc[i][j];
                sm.Ssc[ty4 + i][c] = __fadd_rn(lf, bc[c]);
            }
        }
    __syncthreads();

    // per-row fp64 softmax + threshold; threads 0..31 (one row each)
    if (tid < 32) {
        const int p = row0 + tid;
        const int b = p / PP_;
        const int pi = p - b * PP_;

        float m = sm.Ssc[tid][0];
        for (int c = 1; c < CC_; ++c) m = fmaxf(m, sm.Ssc[tid][c]);
        double denom = 0.0;
        for (int c = 0; c < CC_; ++c)
            denom += exp((double)sm.Ssc[tid][c] - (double)m);

        for (int c = 1; c < CC_; ++c) {
            const double sd = exp((double)sm.Ssc[tid][c] - (double)m) / denom;
            const float score = (float)sd;
            if (score > SCORE_TH) {
                const int pos = atomicAdd(&cnt[b], 1);
                if (pos < CAP_) {
                    const int g = b * CAP_ + pos;
                    cs[g] = score;
                    clab[g] = c;
                    corig[g] = pi * (CC_ - 1) + (c - 1);
                    cpidx[g] = p;
                }
            }
        }
    }
}

// ---------------------------------------------------------------------------
// Kernel 2: per-candidate box regression (FP64 dot) + strict-fp32 decode.
// (unchanged — bit-exact)
// ---------------------------------------------------------------------------
__global__ __launch_bounds__(256) void decode_cand(
    const float* __restrict__ A, const float* __restrict__ Wb,
    const float* __restrict__ bb, const float* __restrict__ props,
    const int* __restrict__ cnt, const int* __restrict__ clab,
    const int* __restrict__ cpidx,
    float* __restrict__ cs, float* __restrict__ cx1, float* __restrict__ cy1,
    float* __restrict__ cx2, float* __restrict__ cy2)
{
    const int wid = (blockIdx.x * 256 + threadIdx.x) >> 6;
    const int lane = threadIdx.x & 63;
    const int b = wid / CAP_;
    const int pos = wid - b * CAP_;
    if (b >= BB_) return;
    const int n = min(cnt[b], CAP_);
    if (pos >= n) return;

    const int g = b * CAP_ + pos;
    const int p = cpidx[g];
    const int c = clab[g];

    const float* fr = A + (size_t)p * FF_;
    const float* wb0 = Wb + 4 * c;

    double a0 = 0.0, a1 = 0.0, a2 = 0.0, a3 = 0.0;
    for (int k = lane; k < FF_; k += 64) {
        const double f = (double)fr[k];
        const float4 wv = *reinterpret_cast<const float4*>(wb0 + (size_t)k * (CC_ * 4));
        a0 += f * (double)wv.x; a1 += f * (double)wv.y;
        a2 += f * (double)wv.z; a3 += f * (double)wv.w;
    }
#pragma unroll
    for (int off = 32; off > 0; off >>= 1) {
        a0 += __shfl_xor(a0, off);
        a1 += __shfl_xor(a1, off);
        a2 += __shfl_xor(a2, off);
        a3 += __shfl_xor(a3, off);
    }

    if (lane == 0) {
        const float dx = __fadd_rn((float)a0, bb[4 * c + 0]);
        const float dy = __fadd_rn((float)a1, bb[4 * c + 1]);
        const float clipf = (float)BBOX_CLIP_D;
        const float dw = fminf(__fadd_rn((float)a2, bb[4 * c + 2]), clipf);
        const float dh = fminf(__fadd_rn((float)a3, bb[4 * c + 3]), clipf);

        const float px1 = props[(size_t)p * 4 + 0];
        const float py1 = props[(size_t)p * 4 + 1];
        const float px2 = props[(size_t)p * 4 + 2];
        const float py2 = props[(size_t)p * 4 + 3];
        const float w = __fsub_rn(px2, px1);
        const float h = __fsub_rn(py2, py1);
        const float cx = __fadd_rn(px1, __fmul_rn(0.5f, w));
        const float cy = __fadd_rn(py1, __fmul_rn(0.5f, h));

        const float pcx = __fadd_rn(__fmul_rn(dx, w), cx);
        const float pcy = __fadd_rn(__fmul_rn(dy, h), cy);
        const float ew = (float)exp((double)dw);
        const float eh = (float)exp((double)dh);
        const float pw = __fmul_rn(ew, w);
        const float ph = __fmul_rn(eh, h);

        const float hw = __fmul_rn(0.5f, pw);
        const float hh = __fmul_rn(0.5f, ph);
        const float bx1 = fminf(fmaxf(__fsub_rn(pcx, hw), 0.f), IMG_W);
        const float by1 = fminf(fmaxf(__fsub_rn(pcy, hh), 0.f), IMG_H);
        const float bx2 = fminf(fmaxf(__fadd_rn(pcx, hw), 0.f), IMG_W);
        const float by2 = fminf(fmaxf(__fadd_rn(pcy, hh), 0.f), IMG_H);

        cx1[g] = bx1; cy1[g] = by1; cx2[g] = bx2; cy2[g] = by2;
        if (!(__fsub_rn(bx2, bx1) >= MIN_SZ && __fsub_rn(by2, by1) >= MIN_SZ)) {
            cs[g] = -INFINITY;
        }
    }
}

// ---------------------------------------------------------------------------
// Kernel 3: per-(image,class) greedy NMS — one wave per (b,c) pair.
// Identical selection set to global class-offset greedy (cross-class IoU = 0),
// same __f*_rn IoU bits. Survivors appended (order-free) with packed key.
// ---------------------------------------------------------------------------
__global__ __launch_bounds__(64) void nms_class(
    const float* __restrict__ c_x1, const float* __restrict__ c_y1,
    const float* __restrict__ c_x2, const float* __restrict__ c_y2,
    const float* __restrict__ c_s, const int* __restrict__ c_lab,
    const int* __restrict__ c_orig, const int* __restrict__ cnt,
    ull* __restrict__ skey, float* __restrict__ sx1v, float* __restrict__ sy1v,
    float* __restrict__ sx2v, float* __restrict__ sy2v,
    int* __restrict__ slabv, int* __restrict__ scnt)
{
    const int blk = blockIdx.x;
    const int b = blk / (CC_ - 1);
    const int c = 1 + (blk - b * (CC_ - 1));
    const int lane = threadIdx.x;

    __shared__ ull kk[CLS_CAP];
    __shared__ float x1s[CLS_CAP], y1s[CLS_CAP], x2s[CLS_CAP], y2s[CLS_CAP];

    const int n = min(cnt[b], CAP_);

    // gather this class's live candidates (ballot compaction)
    int mcnt = 0;
    for (int i0 = 0; i0 < n; i0 += 64) {
        const int i = i0 + lane;
        bool take = false;
        float s = 0.f; int so = 0; int g = 0;
        if (i < n) {
            g = b * CAP_ + i;
            if (c_lab[g] == c) {
                s = c_s[g];
                if (s > 0.f) { take = true; so = c_orig[g]; }
            }
        }
        const ull bal = __ballot(take);
        if (take) {
            const int pos = mcnt + __popcll(bal & ((1ull << lane) - 1ull));
            if (pos < CLS_CAP) {
                kk[pos] = ((ull)__float_as_uint(s) << 32) |
                          (unsigned int)(0x7FFFFFFF - so);
                x1s[pos] = c_x1[g]; y1s[pos] = c_y1[g];
                x2s[pos] = c_x2[g]; y2s[pos] = c_y2[g];
            }
        }
        mcnt += (int)__popcll(bal);
    }
    mcnt = min(mcnt, CLS_CAP);
    if (mcnt == 0) return;
    __syncthreads();   // LDS visibility within the wave

    while (true) {
        // wave argmax over keys
        ull best = 0ull;
        for (int i = lane; i < mcnt; i += 64) best = (kk[i] > best) ? kk[i] : best;
#pragma unroll
        for (int off = 32; off > 0; off >>= 1) {
            const ull o = __shfl_xor(best, off);
            best = (o > best) ? o : best;
        }
        if (best == 0ull) break;

        // locate winner (keys unique)
        int wsl = -1;
        for (int i = lane; i < mcnt; i += 64) if (kk[i] == best) wsl = i;
        const ull bal = __ballot(wsl >= 0);
        const int wlane = (int)__ffsll((long long)bal) - 1;
        wsl = __shfl(wsl, wlane);

        const float wx1 = x1s[wsl], wy1 = y1s[wsl];
        const float wx2 = x2s[wsl], wy2 = y2s[wsl];

        if (lane == 0) {
            const int sp = atomicAdd(&scnt[b], 1);
            if (sp < SURV_CAP) {
                const int sg = b * SURV_CAP + sp;
                skey[sg] = best;
                sx1v[sg] = wx1; sy1v[sg] = wy1;
                sx2v[sg] = wx2; sy2v[sg] = wy2;
                slabv[sg] = c;
            }
        }

        // suppress same-class (exact offset-space fp32 arithmetic)
        const float off = __fmul_rn((float)c, OFF_);
        const float ax1 = __fadd_rn(wx1, off), ay1 = __fadd_rn(wy1, off);
        const float ax2 = __fadd_rn(wx2, off), ay2 = __fadd_rn(wy2, off);
        const float a1 = __fmul_rn(__fsub_rn(ax2, ax1), __fsub_rn(ay2, ay1));
        for (int i = lane; i < mcnt; i += 64) {
            if (kk[i] == 0ull) continue;
            const float bx1 = __fadd_rn(x1s[i], off), by1 = __fadd_rn(y1s[i], off);
            const float bx2 = __fadd_rn(x2s[i], off), by2 = __fadd_rn(y2s[i], off);
            const float ix1 = fmaxf(ax1, bx1), iy1 = fmaxf(ay1, by1);
            const float ix2 = fminf(ax2, bx2), iy2 = fminf(ay2, by2);
            const float inter = __fmul_rn(fmaxf(__fsub_rn(ix2, ix1), 0.f),
                                          fmaxf(__fsub_rn(iy2, iy1), 0.f));
            const float a2 = __fmul_rn(__fsub_rn(bx2, bx1), __fsub_rn(by2, by1));
            const float den = __fadd_rn(__fsub_rn(__fadd_rn(a1, a2), inter), 1e-9f);
            const float iou = __fdiv_rn(inter, den);
            if (iou > NMS_TH) kk[i] = 0ull;   // winner dies too (iou=1)
        }
        __syncthreads();
    }
}

// ---------------------------------------------------------------------------
// Kernel 4: per-image merge — bitonic sort survivors by key (desc), emit
// top-100 in order. Key order == global greedy pick order.
// ---------------------------------------------------------------------------
__global__ __launch_bounds__(256) void nms_merge(
    const ull* __restrict__ skey, const float* __restrict__ sx1v,
    const float* __restrict__ sy1v, const float* __restrict__ sx2v,
    const float* __restrict__ sy2v, const int* __restrict__ slabv,
    const int* __restrict__ scnt, float* __restrict__ out)
{
    const int b = blockIdx.x;
    const int t = threadIdx.x;

    __shared__ ull k_[SURV_CAP];
    __shared__ int id_[SURV_CAP];

    const int m = min(scnt[b], SURV_CAP);
    int N2 = 128;
    while (N2 < m) N2 <<= 1;

    for (int i = t; i < N2; i += 256) {
        k_[i] = (i < m) ? skey[b * SURV_CAP + i] : 0ull;
        id_[i] = i;
    }
    __syncthreads();

    for (int ksz = 2; ksz <= N2; ksz <<= 1) {
        for (int j = ksz >> 1; j > 0; j >>= 1) {
            for (int i = t; i < N2; i += 256) {
                const int ixj = i ^ j;
                if (ixj > i) {
                    const ull a = k_[i], cc = k_[ixj];
                    const bool desc = ((i & ksz) == 0);
                    if (desc ? (a < cc) : (a > cc)) {
                        k_[i] = cc; k_[ixj] = a;
                        const int tmp = id_[i]; id_[i] = id_[ixj]; id_[ixj] = tmp;
                    }
                }
            }
            __syncthreads();
        }
    }

    const int boxes_base = 0;
    const int scores_base = BB_ * DETS_ * 4;
    const int labels_base = BB_ * DETS_ * 5;

    for (int r = t; r < DETS_; r += 256) {
        const ull key = (r < N2) ? k_[r] : 0ull;
        float* bo = out + boxes_base + (size_t)(b * DETS_ + r) * 4;
        if (key != 0ull) {
            const int sg = b * SURV_CAP + id_[r];
            bo[0] = sx1v[sg]; bo[1] = sy1v[sg];
            bo[2] = sx2v[sg]; bo[3] = sy2v[sg];
            out[scores_base + b * DETS_ + r] = __uint_as_float((unsigned)(key >> 32));
            out[labels_base + b * DETS_ + r] = (float)slabv[sg];
        } else {
            bo[0] = 0.f; bo[1] = 0.f; bo[2] = 0.f; bo[3] = 0.f;
            out[scores_base + b * DETS_ + r] = 0.f;
            out[labels_base + b * DETS_ + r] = 0.f;
        }
    }
}

// ---------------------------------------------------------------------------
extern "C" void kernel_launch(void* const* d_in, const int* in_sizes, int n_in,
                              void* d_out, int out_size, void* d_ws, size_t ws_size,
                              hipStream_t stream)
{
    const float* feat  = (const float*)d_in[0];
    const float* Wc    = (const float*)d_in[1];
    const float* bc    = (const float*)d_in[2];
    const float* Wb    = (const float*)d_in[3];
    const float* bb    = (const float*)d_in[4];
    const float* props = (const float*)d_in[5];
    for (int i = 0; i < n_in; ++i) {
        const float* q = (const float*)d_in[i];
        switch (in_sizes[i]) {
            case 16384000: feat  = q; break;  // [16000,1024]
            case 93184:    Wc    = q; break;  // [1024,91]
            case 91:       bc    = q; break;
            case 372736:   Wb    = q; break;  // [1024,364]
            case 364:      bb    = q; break;
            case 64000:    props = q; break;  // [16,1000,4]
        }
    }
    float* out = (float*)d_out;

    char* ws = (char*)d_ws;
    int*   cnt   = (int*)ws;            // 16 ints
    int*   scnt  = (int*)(ws + 64);     // 16 ints
    float* cs    = (float*)(ws + 256);
    int*   clab  = (int*)(cs + CAND_MAX);
    int*   corig = clab + CAND_MAX;
    int*   cpidx = corig + CAND_MAX;
    float* cx1   = (float*)(cpidx + CAND_MAX);
    float* cy1   = cx1 + CAND_MAX;
    float* cx2   = cy1 + CAND_MAX;
    float* cy2   = cx2 + CAND_MAX;
    ull*   skey  = (ull*)(cy2 + CAND_MAX);
    float* sx1v  = (float*)(skey + (size_t)BB_ * SURV_CAP);
    float* sy1v  = sx1v + (size_t)BB_ * SURV_CAP;
    float* sx2v  = sy1v + (size_t)BB_ * SURV_CAP;
    float* sy2v  = sx2v + (size_t)BB_ * SURV_CAP;
    int*   slabv = (int*)(sy2v + (size_t)BB_ * SURV_CAP);

    hipMemsetAsync(ws, 0, 256, stream);   // zero cnt + scnt

    logits_cand<<<500, 256, 0, stream>>>(feat, Wc, bc,
        cs, clab, corig, cpidx, cnt);

    decode_cand<<<CAND_MAX / 4, 256, 0, stream>>>(feat, Wb, bb, props,
        cnt, clab, cpidx, cs, cx1, cy1, cx2, cy2);

    nms_class<<<BB_ * (CC_ - 1), 64, 0, stream>>>(
        cx1, cy1, cx2, cy2, cs, clab, corig, cnt,
        skey, sx1v, sy1v, sx2v, sy2v, slabv, scnt);

    nms_merge<<<BB_, 256, 0, stream>>>(
        skey, sx1v, sy1v, sx2v, sy2v, slabv, scnt, out);
}